// Round 1
// baseline (255.784 us; speedup 1.0000x reference)
//
#include <hip/hip_runtime.h>

// LSTMClassifier: B=4096, T=128, I=32, H=64, 2-layer LSTM + MLP head.
// Round 4 (from R3's 206us/120us-dispatch baseline):
//  - removed xs[] LDS staging: each L0 wave loads its x A-fragment directly
//    from global (redundant x4, L2/L3-resident), pipelined 2 steps ahead.
//  - x*Wih0 MFMAs hoisted off the barrier-gated critical path: xacc(k+1)
//    computed during step k; per-step L0 chain is now 2 MFMAs deep (h-part).
//  - biases folded into eltwise exp2 args as fma constants; acc chains start
//    from xacc/zero quad -> no per-step 16x v_mov acc init.
//  - fmed3 clamp (scaled bounds) instead of fminf/fmaxf.
// Structure: 256 blocks x 512 thr (8 waves); waves 0-3 layer0 step k,
// waves 4-7 layer1 step k-1; double-buffered f16 h-state in LDS, ONE
// barrier per timestep. f16 MFMA operands, fp32 accumulate/state.

#define TT 128
#define II 32

typedef _Float16 half8 __attribute__((ext_vector_type(8)));
typedef float floatx4 __attribute__((ext_vector_type(4)));

#define LOG2E 1.4426950408889634f

__device__ __forceinline__ half8 cvt_frag(float4 a, float4 b) {
    half8 h;
    h[0] = (_Float16)a.x; h[1] = (_Float16)a.y; h[2] = (_Float16)a.z; h[3] = (_Float16)a.w;
    h[4] = (_Float16)b.x; h[5] = (_Float16)b.y; h[6] = (_Float16)b.z; h[7] = (_Float16)b.w;
    return h;
}

// Load 8 consecutive fp32 of row n (K-major) as an f16 MFMA B-fragment.
__device__ __forceinline__ half8 load_w_frag(const float* __restrict__ W, int n, int K, int k0) {
    const float* p = W + (size_t)n * K + k0;
    return cvt_frag(*(const float4*)p, *(const float4*)(p + 4));
}

__global__ __launch_bounds__(512, 2) void lstm_fused(
    const float* __restrict__ x,
    const float* __restrict__ Wih0, const float* __restrict__ Whh0,
    const float* __restrict__ bih0, const float* __restrict__ bhh0,
    const float* __restrict__ Wih1, const float* __restrict__ Whh1,
    const float* __restrict__ bih1, const float* __restrict__ bhh1,
    const float* __restrict__ Wc1, const float* __restrict__ bc1,
    const float* __restrict__ Wc2, const float* __restrict__ bc2,
    float* __restrict__ out)
{
    // Double-buffered h-state; stride 72 f16 (144B) keeps b128 reads at a
    // free 2-way bank alias (m136).
    __shared__ __align__(16) _Float16 h0s[2][16][72];
    __shared__ __align__(16) _Float16 h1s[2][16][72];
    __shared__ __align__(16) float h1f[16][68];   // final-step h1 (fp32) for classifier
    __shared__ float hid[16][32];

    const int tid  = threadIdx.x;
    const int wid  = tid >> 6;        // wave 0..7
    const int w4   = wid & 3;         // channel-group within the layer
    const bool isL0 = (wid < 4);
    const int lane = tid & 63;
    const int q  = lane >> 4;         // quad 0..3
    const int lr = lane & 15;
    const int b0 = blockIdx.x * 16;

    const float nL  = -LOG2E;         // sigmoid arg scale
    const float p2L = 2.0f * LOG2E;   // tanh arg scale
    const float C43 = 30.0f * LOG2E;  // = |15 * 2L| clamp bound (post-scale)

    // ---- persistent weight fragments (registers, whole kernel) ----
    // Wave group w4 owns gate-column tiles n = (w4 + 4g)*16: all four gates
    // for channels [16*w4, 16*w4+16) are lane-local at eltwise.
    half8 bx0[4], bh0[4][2];          // layer-0 waves
    half8 bi1[4][2], bh1[4][2];       // layer-1 waves
    float bias[4];
    if (isL0) {
        #pragma unroll
        for (int g = 0; g < 4; ++g) {
            int n = (w4 + 4 * g) * 16 + lr;
            bx0[g]    = load_w_frag(Wih0, n, 32, q * 8);
            bh0[g][0] = load_w_frag(Whh0, n, 64, q * 8);
            bh0[g][1] = load_w_frag(Whh0, n, 64, 32 + q * 8);
            bias[g]   = bih0[n] + bhh0[n];
        }
    } else {
        #pragma unroll
        for (int g = 0; g < 4; ++g) {
            int n = (w4 + 4 * g) * 16 + lr;
            bi1[g][0] = load_w_frag(Wih1, n, 64, q * 8);
            bi1[g][1] = load_w_frag(Wih1, n, 64, 32 + q * 8);
            bh1[g][0] = load_w_frag(Whh1, n, 64, q * 8);
            bh1[g][1] = load_w_frag(Whh1, n, 64, 32 + q * 8);
            bias[g]   = bih1[n] + bhh1[n];
        }
    }
    // pre-scaled biases: fold into the eltwise exp2-arg fmas (i,f,g,o order)
    const float nbi = nL * bias[0], nbf = nL * bias[1];
    const float bg2 = p2L * bias[2], nbo = nL * bias[3];

    const floatx4 zeroq = {0.f, 0.f, 0.f, 0.f};

    // ---- x fragments straight from global, 2 steps ahead (L0 waves) ----
    // lane (q,lr): A-frag row lr, channels [8q, 8q+8): 2x dwordx4 per step.
    const float* xlane = x + (size_t)(b0 + lr) * TT * II + q * 8;
    float4 xr0, xr1;                  // raw fp32 x(k+1)
    floatx4 xacc[4];                  // bias-free x(k)*Wih0^T, ready at step k
    if (isL0) {
        half8 xf = cvt_frag(*(const float4*)xlane, *(const float4*)(xlane + 4));
        #pragma unroll
        for (int g = 0; g < 4; ++g)
            xacc[g] = __builtin_amdgcn_mfma_f32_16x16x32_f16(xf, bx0[g], zeroq, 0, 0, 0);
        xr0 = *(const float4*)(xlane + II);
        xr1 = *(const float4*)(xlane + II + 4);
    }

    // zero-init both h-state buffers (h0(-1) = h1(-1) = 0)
    for (int i = tid; i < 2 * 16 * 72; i += 512) {
        ((_Float16*)h0s)[i] = (_Float16)0.0f;
        ((_Float16*)h1s)[i] = (_Float16)0.0f;
    }

    float cr[4] = {0.f, 0.f, 0.f, 0.f};   // c state for this wave's layer

    // Iteration k: waves 0-3 compute h0(k) (k < TT); waves 4-7 compute
    // h1(k-1) (k >= 1). h*(k) -> buf[k&1]; iter k reads h*(k-1) from
    // buf[(k+1)&1]. One barrier per iter.
    for (int k = 0; k <= TT; ++k) {
        __syncthreads();

        const int rd = (k + 1) & 1;
        const int wr = k & 1;
        const bool doL0 = isL0 && (k < TT);
        const bool doL1 = (!isL0) && (k >= 1);
        floatx4 a[4];
        float hnew[4];

        if (doL0) {
            // gates(raw) = xacc(k) + h0(k-1) Whh0^T   (bias folded into eltwise)
            half8 h0a = *(const half8*)&h0s[rd][lr][q * 8];
            half8 h0b = *(const half8*)&h0s[rd][lr][32 + q * 8];
            #pragma unroll
            for (int g = 0; g < 4; ++g) {
                floatx4 t = __builtin_amdgcn_mfma_f32_16x16x32_f16(h0a, bh0[g][0], xacc[g], 0, 0, 0);
                a[g]      = __builtin_amdgcn_mfma_f32_16x16x32_f16(h0b, bh0[g][1], t,       0, 0, 0);
            }
        }
        if (doL1) {
            // gates(raw) = h0(k-1) Wih1^T + h1(k-2) Whh1^T
            half8 g0a = *(const half8*)&h0s[rd][lr][q * 8];
            half8 g0b = *(const half8*)&h0s[rd][lr][32 + q * 8];
            half8 h1a = *(const half8*)&h1s[rd][lr][q * 8];
            half8 h1b = *(const half8*)&h1s[rd][lr][32 + q * 8];
            #pragma unroll
            for (int g = 0; g < 4; ++g) {
                floatx4 t = __builtin_amdgcn_mfma_f32_16x16x32_f16(g0a, bi1[g][0], zeroq, 0, 0, 0);
                t         = __builtin_amdgcn_mfma_f32_16x16x32_f16(g0b, bi1[g][1], t,     0, 0, 0);
                t         = __builtin_amdgcn_mfma_f32_16x16x32_f16(h1a, bh1[g][0], t,     0, 0, 0);
                a[g]      = __builtin_amdgcn_mfma_f32_16x16x32_f16(h1b, bh1[g][1], t,     0, 0, 0);
            }
        }
        if (doL0 || doL1) {
            // eltwise, biases folded: sig(x+b) = rcp(1+exp2(nL*x + nb));
            // sig(a+ba)*tanh(g+bg) = (u-1)*rcp((1+v)(u+1)),
            //   u = exp2(clamp(p2L*g + bg2)), v = exp2(nL*a + nba).
            #pragma unroll
            for (int r = 0; r < 4; ++r) {
                float vf = __builtin_amdgcn_exp2f(fmaf(a[1][r], nL, nbf));
                float sf = __builtin_amdgcn_rcpf(1.0f + vf);
                float tg = __builtin_amdgcn_fmed3f(fmaf(a[2][r], p2L, bg2), -C43, C43);
                float u  = __builtin_amdgcn_exp2f(tg);
                float vi = __builtin_amdgcn_exp2f(fmaf(a[0][r], nL, nbi));
                float d1 = u + 1.0f;
                float st = (u - 1.0f) * __builtin_amdgcn_rcpf(fmaf(vi, d1, d1));
                float c  = fmaf(sf, cr[r], st);
                cr[r] = c;
                float vo = __builtin_amdgcn_exp2f(fmaf(a[3][r], nL, nbo));
                float tc = __builtin_amdgcn_fmed3f(c * p2L, -C43, C43);
                float uc = __builtin_amdgcn_exp2f(tc);
                float dc = uc + 1.0f;
                hnew[r] = (uc - 1.0f) * __builtin_amdgcn_rcpf(fmaf(vo, dc, dc));
            }
        }

        // writes go to buf[wr]; readers of buf[wr] are past the next barrier
        if (doL0) {
            #pragma unroll
            for (int r = 0; r < 4; ++r)
                h0s[wr][q * 4 + r][w4 * 16 + lr] = (_Float16)hnew[r];
            if (k + 1 < TT) {
                // barrier-shadow work: x(k+1)*Wih0^T for next step + issue
                // x(k+2) loads (drained by the k+2-top barrier, ~2 steps away)
                half8 xf = cvt_frag(xr0, xr1);
                if (k + 2 < TT) {
                    xr0 = *(const float4*)(xlane + (size_t)(k + 2) * II);
                    xr1 = *(const float4*)(xlane + (size_t)(k + 2) * II + 4);
                }
                #pragma unroll
                for (int g = 0; g < 4; ++g)
                    xacc[g] = __builtin_amdgcn_mfma_f32_16x16x32_f16(xf, bx0[g], zeroq, 0, 0, 0);
            }
        }
        if (doL1) {
            if (k == TT) {
                #pragma unroll
                for (int r = 0; r < 4; ++r)
                    h1f[q * 4 + r][w4 * 16 + lr] = hnew[r];
            } else {
                #pragma unroll
                for (int r = 0; r < 4; ++r)
                    h1s[wr][q * 4 + r][w4 * 16 + lr] = (_Float16)hnew[r];
            }
        }
    }
    __syncthreads();

    // ---- classifier (fp32): hidden = relu(hT Wc1^T + bc1); out = hidden Wc2^T + bc2
    if (tid < 256) {
        int m = tid >> 4;
        int u = (tid & 15) * 2;
        float aa = bc1[u], bb = bc1[u + 1];
        const float* w0 = Wc1 + u * 64;
        const float* w1 = Wc1 + (u + 1) * 64;
        #pragma unroll 8
        for (int kk = 0; kk < 64; ++kk) {
            float hv = h1f[m][kk];
            aa += hv * w0[kk];
            bb += hv * w1[kk];
        }
        hid[m][u]     = fmaxf(aa, 0.f);
        hid[m][u + 1] = fmaxf(bb, 0.f);
    }
    __syncthreads();
    if (tid < 16) {
        float o = bc2[0];
        #pragma unroll
        for (int u = 0; u < 32; ++u) o += hid[tid][u] * Wc2[u];
        out[b0 + tid] = o;
    }
}

extern "C" void kernel_launch(void* const* d_in, const int* in_sizes, int n_in,
                              void* d_out, int out_size, void* d_ws, size_t ws_size,
                              hipStream_t stream) {
    (void)in_sizes; (void)n_in; (void)d_ws; (void)ws_size; (void)out_size;
    const float* x    = (const float*)d_in[0];
    const float* Wih0 = (const float*)d_in[1];
    const float* Whh0 = (const float*)d_in[2];
    const float* bih0 = (const float*)d_in[3];
    const float* bhh0 = (const float*)d_in[4];
    const float* Wih1 = (const float*)d_in[5];
    const float* Whh1 = (const float*)d_in[6];
    const float* bih1 = (const float*)d_in[7];
    const float* bhh1 = (const float*)d_in[8];
    const float* Wc1  = (const float*)d_in[9];
    const float* bc1  = (const float*)d_in[10];
    const float* Wc2  = (const float*)d_in[11];
    const float* bc2  = (const float*)d_in[12];
    lstm_fused<<<dim3(256), dim3(512), 0, stream>>>(
        x, Wih0, Whh0, bih0, bhh0, Wih1, Whh1, bih1, bhh1, Wc1, bc1, Wc2, bc2,
        (float*)d_out);
}

// Round 2
// 217.024 us; speedup vs baseline: 1.1786x; 1.1786x over previous
//
#include <hip/hip_runtime.h>

// LSTMClassifier: B=4096, T=128, I=32, H=64, 2-layer LSTM + MLP head.
// Round 5: barrier-free producer/consumer wave groups.
//   Grid is 256 blocks on 256 CUs = 1 workgroup/CU -> the single
//   __syncthreads per step lockstepped all 8 waves (45% idle in R3).
//   Now: waves 0-3 (L0 group) and waves 4-7 (L1 group) are decoupled via
//   LDS sequence counters (release ds_atomic_add / acquire spin + s_sleep).
//   h0 flows through an 8-deep LDS ring so L0 free-runs ahead of L1; each
//   SIMD hosts one L0 + one L1 wave at DIFFERENT phases -> latency overlap.
// x-path: R3-style shared LDS staging (one cvt per element per block).
// Eltwise: R4's validated folded-bias form (zero-C MFMA chains, fmed3).
// f16 MFMA operands, fp32 accumulate/state.

#define TT 128
#define II 32
#define D0 8            // h0 ring depth (power of 2)

typedef _Float16 half8 __attribute__((ext_vector_type(8)));
typedef float floatx4 __attribute__((ext_vector_type(4)));

#define LOG2E 1.4426950408889634f

__device__ __forceinline__ half8 cvt_frag(float4 a, float4 b) {
    half8 h;
    h[0] = (_Float16)a.x; h[1] = (_Float16)a.y; h[2] = (_Float16)a.z; h[3] = (_Float16)a.w;
    h[4] = (_Float16)b.x; h[5] = (_Float16)b.y; h[6] = (_Float16)b.z; h[7] = (_Float16)b.w;
    return h;
}

// Load 8 consecutive fp32 of row n (K-major) as an f16 MFMA B-fragment.
__device__ __forceinline__ half8 load_w_frag(const float* __restrict__ W, int n, int K, int k0) {
    const float* p = W + (size_t)n * K + k0;
    return cvt_frag(*(const float4*)p, *(const float4*)(p + 4));
}

// Spin until *p >= v. Counters are monotonically increasing. Acquire orders
// the subsequent LDS reads; s_sleep keeps a waiting wave off the issue ports.
__device__ __forceinline__ void wait_ge(int* p, int v) {
    while (__hip_atomic_load(p, __ATOMIC_ACQUIRE, __HIP_MEMORY_SCOPE_WORKGROUP) < v)
        __builtin_amdgcn_s_sleep(1);
}

// LSTM cell eltwise, biases pre-folded into the exp2 args (i,f,g,o order):
//   sig(x+b)        = rcp(1 + exp2(nL*x + nb))
//   sig(a)*tanh(g)  = (u-1) * rcp((1+v)(u+1)),  u = exp2(clamp(p2L*g + bg2))
__device__ __forceinline__ void lstm_cell(const floatx4* a, float* cr, float* hnew,
                                          float nbi, float nbf, float bg2, float nbo) {
    const float nL  = -LOG2E;
    const float p2L = 2.0f * LOG2E;
    const float C43 = 30.0f * LOG2E;   // |15 * 2L| clamp bound (post-scale)
    #pragma unroll
    for (int r = 0; r < 4; ++r) {
        float vf = __builtin_amdgcn_exp2f(fmaf(a[1][r], nL, nbf));
        float sf = __builtin_amdgcn_rcpf(1.0f + vf);
        float tg = __builtin_amdgcn_fmed3f(fmaf(a[2][r], p2L, bg2), -C43, C43);
        float u  = __builtin_amdgcn_exp2f(tg);
        float vi = __builtin_amdgcn_exp2f(fmaf(a[0][r], nL, nbi));
        float d1 = u + 1.0f;
        float st = (u - 1.0f) * __builtin_amdgcn_rcpf(fmaf(vi, d1, d1));
        float c  = fmaf(sf, cr[r], st);
        cr[r] = c;
        float vo = __builtin_amdgcn_exp2f(fmaf(a[3][r], nL, nbo));
        float tc = __builtin_amdgcn_fmed3f(c * p2L, -C43, C43);
        float uc = __builtin_amdgcn_exp2f(tc);
        float dc = uc + 1.0f;
        hnew[r] = (uc - 1.0f) * __builtin_amdgcn_rcpf(fmaf(vo, dc, dc));
    }
}

__global__ __launch_bounds__(512, 2) void lstm_fused(
    const float* __restrict__ x,
    const float* __restrict__ Wih0, const float* __restrict__ Whh0,
    const float* __restrict__ bih0, const float* __restrict__ bhh0,
    const float* __restrict__ Wih1, const float* __restrict__ Whh1,
    const float* __restrict__ bih1, const float* __restrict__ bhh1,
    const float* __restrict__ Wc1, const float* __restrict__ bc1,
    const float* __restrict__ Wc2, const float* __restrict__ bc2,
    float* __restrict__ out)
{
    // 72-f16 row stride (144B) keeps b128 reads at a cheap bank alias.
    __shared__ __align__(16) _Float16 xs[2][16][40];     // x(t) staging, f16
    __shared__ __align__(16) _Float16 h0s[D0][16][72];   // h0 ring, 8 deep
    __shared__ __align__(16) _Float16 h1s[2][16][72];    // h1 double buffer
    __shared__ __align__(16) float h1f[16][68];          // final h1 (fp32)
    __shared__ float hid[16][32];
    __shared__ int c0[TT + 1];    // c0[t] = #L0 waves done with step t
    __shared__ int c1[TT + 1];    // c1[t] = #L1 waves done with step t

    const int tid  = threadIdx.x;
    const int wid  = tid >> 6;        // wave 0..7 (round-robin -> SIMD wid%4:
    const int w4   = wid & 3;         //   each SIMD gets one L0 + one L1 wave)
    const bool isL0 = (wid < 4);
    const int lane = tid & 63;
    const int q  = lane >> 4;         // quad 0..3
    const int lr = lane & 15;
    const int b0 = blockIdx.x * 16;

    const float nL  = -LOG2E;
    const float p2L = 2.0f * LOG2E;

    // ---- persistent weight fragments (registers, whole kernel) ----
    // Wave group w4 owns gate-column tiles n = (w4 + 4g)*16: all four gates
    // for channels [16*w4, 16*w4+16) are lane-local at eltwise.
    half8 bx0[4], bh0[4][2];          // layer-0 waves
    half8 bi1[4][2], bh1[4][2];       // layer-1 waves
    float bias[4];
    if (isL0) {
        #pragma unroll
        for (int g = 0; g < 4; ++g) {
            int n = (w4 + 4 * g) * 16 + lr;
            bx0[g]    = load_w_frag(Wih0, n, 32, q * 8);
            bh0[g][0] = load_w_frag(Whh0, n, 64, q * 8);
            bh0[g][1] = load_w_frag(Whh0, n, 64, 32 + q * 8);
            bias[g]   = bih0[n] + bhh0[n];
        }
    } else {
        #pragma unroll
        for (int g = 0; g < 4; ++g) {
            int n = (w4 + 4 * g) * 16 + lr;
            bi1[g][0] = load_w_frag(Wih1, n, 64, q * 8);
            bi1[g][1] = load_w_frag(Wih1, n, 64, 32 + q * 8);
            bh1[g][0] = load_w_frag(Whh1, n, 64, q * 8);
            bh1[g][1] = load_w_frag(Whh1, n, 64, 32 + q * 8);
            bias[g]   = bih1[n] + bhh1[n];
        }
    }
    const float nbi = nL * bias[0], nbf = nL * bias[1];
    const float bg2 = p2L * bias[2], nbo = nL * bias[3];
    const floatx4 zeroq = {0.f, 0.f, 0.f, 0.f};

    // init: zero the t=-1 ring slots (uniform loops, no t==0 branches) and
    // the sequence counters.
    for (int i = tid; i < 16 * 72; i += 512) {
        ((_Float16*)h0s[D0 - 1])[i] = (_Float16)0.0f;   // h0(-1) = 0
        ((_Float16*)h1s[1])[i]      = (_Float16)0.0f;   // h1(-1) = 0
    }
    for (int i = tid; i <= TT; i += 512) { c0[i] = 0; c1[i] = 0; }

    // x staging (L0 waves = 256 threads): thread -> (row xm, 2 floats)
    const int xm = (tid >> 4) & 15;
    const int xf = (tid & 15) * 2;
    const float* xrow = x + ((size_t)(b0 + xm) * TT) * II + xf;
    float2 xbuf = {0.f, 0.f};
    if (isL0) {
        float2 x0 = *(const float2*)(xrow);            // x(0) -> xs[0]
        xs[0][xm][xf]     = (_Float16)x0.x;
        xs[0][xm][xf + 1] = (_Float16)x0.y;
        xbuf = *(const float2*)(xrow + II);            // x(1) in regs
    }
    __syncthreads();   // the ONLY full barrier before the classifier

    float cr[4] = {0.f, 0.f, 0.f, 0.f};
    float hnew[4];
    floatx4 a[4];

    if (isL0) {
        // ---- L0 group: free-running producer ----
        for (int t = 0; t < TT; ++t) {
            if (t > 0)   wait_ge(&c0[t - 1], 4);    // group's h0(t-1)+xs(t) done
            if (t >= D0) wait_ge(&c1[t - D0], 4);   // ring slot reuse guard
            const int rs = (t + D0 - 1) & (D0 - 1); // (t-1) mod D0
            half8 xfrag = *(const half8*)&xs[t & 1][lr][q * 8];
            half8 h0a   = *(const half8*)&h0s[rs][lr][q * 8];
            half8 h0b   = *(const half8*)&h0s[rs][lr][32 + q * 8];
            float2 xnew = xbuf;
            if (t + 2 < TT) xnew = *(const float2*)(xrow + (size_t)(t + 2) * II);
            #pragma unroll
            for (int g = 0; g < 4; ++g) {
                floatx4 acc = __builtin_amdgcn_mfma_f32_16x16x32_f16(xfrag, bx0[g],    zeroq, 0, 0, 0);
                acc         = __builtin_amdgcn_mfma_f32_16x16x32_f16(h0a,   bh0[g][0], acc,   0, 0, 0);
                a[g]        = __builtin_amdgcn_mfma_f32_16x16x32_f16(h0b,   bh0[g][1], acc,   0, 0, 0);
            }
            lstm_cell(a, cr, hnew, nbi, nbf, bg2, nbo);
            #pragma unroll
            for (int r = 0; r < 4; ++r)
                h0s[t & (D0 - 1)][q * 4 + r][w4 * 16 + lr] = (_Float16)hnew[r];
            if (t + 1 < TT) {                       // stage x(t+1) -> xs[(t+1)&1]
                xs[(t + 1) & 1][xm][xf]     = (_Float16)xbuf.x;
                xs[(t + 1) & 1][xm][xf + 1] = (_Float16)xbuf.y;
            }
            xbuf = xnew;
            if (lane == 0)                           // release: writes visible first
                __hip_atomic_fetch_add(&c0[t], 1, __ATOMIC_RELEASE, __HIP_MEMORY_SCOPE_WORKGROUP);
        }
    } else {
        // ---- L1 group: consumer, trails L0 ----
        for (int t = 0; t < TT; ++t) {
            wait_ge(&c0[t], 4);                      // h0(t) ready
            if (t > 0) wait_ge(&c1[t - 1], 4);       // group's h1(t-1) done
            const int hs = t & (D0 - 1);
            const int ps = (t + 1) & 1;              // (t-1) & 1
            half8 g0a = *(const half8*)&h0s[hs][lr][q * 8];
            half8 g0b = *(const half8*)&h0s[hs][lr][32 + q * 8];
            half8 h1a = *(const half8*)&h1s[ps][lr][q * 8];
            half8 h1b = *(const half8*)&h1s[ps][lr][32 + q * 8];
            #pragma unroll
            for (int g = 0; g < 4; ++g) {
                floatx4 acc = __builtin_amdgcn_mfma_f32_16x16x32_f16(g0a, bi1[g][0], zeroq, 0, 0, 0);
                acc         = __builtin_amdgcn_mfma_f32_16x16x32_f16(g0b, bi1[g][1], acc,   0, 0, 0);
                acc         = __builtin_amdgcn_mfma_f32_16x16x32_f16(h1a, bh1[g][0], acc,   0, 0, 0);
                a[g]        = __builtin_amdgcn_mfma_f32_16x16x32_f16(h1b, bh1[g][1], acc,   0, 0, 0);
            }
            lstm_cell(a, cr, hnew, nbi, nbf, bg2, nbo);
            if (t == TT - 1) {
                #pragma unroll
                for (int r = 0; r < 4; ++r)
                    h1f[q * 4 + r][w4 * 16 + lr] = hnew[r];
            } else {
                #pragma unroll
                for (int r = 0; r < 4; ++r)
                    h1s[t & 1][q * 4 + r][w4 * 16 + lr] = (_Float16)hnew[r];
            }
            if (lane == 0)
                __hip_atomic_fetch_add(&c1[t], 1, __ATOMIC_RELEASE, __HIP_MEMORY_SCOPE_WORKGROUP);
        }
    }
    __syncthreads();

    // ---- classifier (fp32): hidden = relu(hT Wc1^T + bc1); out = hidden Wc2^T + bc2
    if (tid < 256) {
        int m = tid >> 4;
        int u = (tid & 15) * 2;
        float aa = bc1[u], bb = bc1[u + 1];
        const float* w0 = Wc1 + u * 64;
        const float* w1 = Wc1 + (u + 1) * 64;
        #pragma unroll 8
        for (int kk = 0; kk < 64; ++kk) {
            float hv = h1f[m][kk];
            aa += hv * w0[kk];
            bb += hv * w1[kk];
        }
        hid[m][u]     = fmaxf(aa, 0.f);
        hid[m][u + 1] = fmaxf(bb, 0.f);
    }
    __syncthreads();
    if (tid < 16) {
        float o = bc2[0];
        #pragma unroll
        for (int u = 0; u < 32; ++u) o += hid[tid][u] * Wc2[u];
        out[b0 + tid] = o;
    }
}

extern "C" void kernel_launch(void* const* d_in, const int* in_sizes, int n_in,
                              void* d_out, int out_size, void* d_ws, size_t ws_size,
                              hipStream_t stream) {
    (void)in_sizes; (void)n_in; (void)d_ws; (void)ws_size; (void)out_size;
    const float* x    = (const float*)d_in[0];
    const float* Wih0 = (const float*)d_in[1];
    const float* Whh0 = (const float*)d_in[2];
    const float* bih0 = (const float*)d_in[3];
    const float* bhh0 = (const float*)d_in[4];
    const float* Wih1 = (const float*)d_in[5];
    const float* Whh1 = (const float*)d_in[6];
    const float* bih1 = (const float*)d_in[7];
    const float* bhh1 = (const float*)d_in[8];
    const float* Wc1  = (const float*)d_in[9];
    const float* bc1  = (const float*)d_in[10];
    const float* Wc2  = (const float*)d_in[11];
    const float* bc2  = (const float*)d_in[12];
    lstm_fused<<<dim3(256), dim3(512), 0, stream>>>(
        x, Wih0, Whh0, bih0, bhh0, Wih1, Whh1, bih1, bhh1, Wc1, bc1, Wc2, bc2,
        (float*)d_out);
}